// Round 7
// baseline (263.129 us; speedup 1.0000x reference)
//
#include <hip/hip_runtime.h>
#include <math.h>
#include <type_traits>

#define NCH 48            // N*C = 16*3
#define WIN 11
#define HALO 10

struct GaussW { float g[WIN]; };

// ---- bf16 <-> f32 bit helpers (RNE pack) ----
__device__ __forceinline__ float bf2f(unsigned u16)      // u16 in low 16 bits
{
    return __uint_as_float(u16 << 16);
}
__device__ __forceinline__ unsigned f2bf(float f)        // returns low-16 bf16
{
    unsigned u = __float_as_uint(f);
    u += 0x7FFFu + ((u >> 16) & 1u);                     // round-to-nearest-even
    return u >> 16;
}

// element load/store wrappers
__device__ __forceinline__ float eload(const unsigned short* p) { return bf2f(*p); }
__device__ __forceinline__ float eload(const float* p)          { return *p; }
__device__ __forceinline__ void  estore(unsigned short* p, float v) { *p = (unsigned short)f2bf(v); }
__device__ __forceinline__ void  estore(float* p, float v)          { *p = v; }

// vertical blur of NOUT consecutive output rows at column c
template<int NOUT, typename ET, int LS, int TBH>
__device__ __forceinline__ void vblur_col(const ET (*sX)[LS], const ET (*sY)[LS],
                                          ET (*vb)[TBH][LS],
                                          int r0, int c, const GaussW& gw)
{
    float a0[NOUT], a1[NOUT], a2[NOUT], a3[NOUT], a4[NOUT];
#pragma unroll
    for (int j = 0; j < NOUT; ++j) { a0[j] = a1[j] = a2[j] = a3[j] = a4[j] = 0.f; }
#pragma unroll
    for (int i = 0; i < NOUT + 10; ++i) {
        float xv = eload(&sX[r0 + i][c]);
        float yv = eload(&sY[r0 + i][c]);
        float xx = xv * xv, yy = yv * yv, xy = xv * yv;
#pragma unroll
        for (int j = 0; j < NOUT; ++j) {
            int k = i - j;
            if (k >= 0 && k < WIN) {
                float gv = gw.g[k];
                a0[j] += gv * xv;
                a1[j] += gv * yv;
                a2[j] += gv * xx;
                a3[j] += gv * yy;
                a4[j] += gv * xy;
            }
        }
    }
#pragma unroll
    for (int j = 0; j < NOUT; ++j) {
        estore(&vb[0][r0 + j][c], a0[j]);
        estore(&vb[1][r0 + j][c], a1[j]);
        estore(&vb[2][r0 + j][c], a2[j]);
        estore(&vb[3][r0 + j][c], a3[j]);
        estore(&vb[4][r0 + j][c], a4[j]);
    }
}

// ---------------------------------------------------------------------------
// Fused per-level kernel: one block = one TBWxTBH output tile of one (n,c).
// LP=true : bf16 LDS. Levels 0-1 only (sigma-cancellation denominator is
//           large there; bf16 vb at level>=2 fails accuracy -- R4 lesson).
// LP=false: fp32 LDS. Levels 2-4.
// launch_bounds(.,4): VGPR cap 128 -> NO spills. R5/R6 lesson: caps 64/80
// forced 32/40-granule allocations and 58-350 MB of scratch traffic.
// Deep levels use 32x32 tiles / 256 threads so the per-block critical path
// (~4 us vs ~14 us) stops dominating the tiny-grid tail.
// ---------------------------------------------------------------------------
template<bool LP, int TBW, int TBH, int NTH>
__global__ __launch_bounds__(NTH, 4)
void ssim_level_kernel(const float* __restrict__ X, const float* __restrict__ Y,
                       int H, int W, int outH, int outW,
                       float* __restrict__ accS2, float* __restrict__ accD,
                       float* __restrict__ poolX, float* __restrict__ poolY,
                       GaussW gw)
{
    using ET = std::conditional_t<LP, unsigned short, float>;
    constexpr int IWT   = TBW + HALO;
    constexpr int IHT   = TBH + HALO;
    constexpr int LS    = LP ? ((IWT + 7) & ~7) : ((IWT + 3) & ~3);
    constexpr int NW    = NTH / 64;          // waves per block
    constexpr int PAIRS = IWT / 2;           // staged element pairs per row
    constexpr int VG    = TBH / 6;           // full 6-row vblur groups
    constexpr int VT    = TBH % 6;           // tail rows
    constexpr int VGT   = VG + (VT ? 1 : 0);
    constexpr int CG    = TBW / 4;           // H-phase column groups

    const int nc  = blockIdx.z;
    const int oy0 = blockIdx.y * TBH;
    const int ox0 = blockIdx.x * TBW;
    const int tid = threadIdx.x;

    const float* __restrict__ Xp = X + (size_t)nc * H * W;
    const float* __restrict__ Yp = Y + (size_t)nc * H * W;

    __shared__ __align__(16) ET sX[IHT][LS];
    __shared__ __align__(16) ET sY[IHT][LS];
    __shared__ __align__(16) ET vb[5][TBH][LS];  // mu1,mu2,xx,yy,xy (V-blurred)
    __shared__ float wpart[2][NW];

    // ---- stage input tile; OOB -> 0 ----
    for (int l = tid; l < IHT * PAIRS; l += NTH) {
        int r  = l / PAIRS, cp = l - r * PAIRS;
        int gy = oy0 + r, gx = ox0 + 2 * cp;
        float2 xv = make_float2(0.f, 0.f), yv = xv;
        if (gy < H && gx < W) {                  // W even, gx even -> gx+1 < W
            size_t idx = (size_t)gy * W + gx;
            xv = *(const float2*)(Xp + idx);
            yv = *(const float2*)(Yp + idx);
        }
        if constexpr (LP) {
            ((unsigned*)sX[r])[cp] = f2bf(xv.x) | (f2bf(xv.y) << 16);
            ((unsigned*)sY[r])[cp] = f2bf(yv.x) | (f2bf(yv.y) << 16);
        } else {
            sX[r][2 * cp]     = xv.x;
            sX[r][2 * cp + 1] = xv.y;
            sY[r][2 * cp]     = yv.x;
            sY[r][2 * cp + 1] = yv.y;
        }
    }
    __syncthreads();

    // ---- fused 2x2 avg-pool of raw TBWxTBH quadrant ----
    if (poolX) {
        int py = tid / (TBW / 2), px = tid % (TBW / 2);  // (TBH/2) x (TBW/2) = NTH
        int pH = H >> 1, pW = W >> 1;
        int ppy = (oy0 >> 1) + py, ppx = (ox0 >> 1) + px;
        if (ppy < pH && ppx < pW) {
            float vx, vy;
            if constexpr (LP) {
                unsigned x0 = ((unsigned*)sX[2 * py])[px];
                unsigned x1 = ((unsigned*)sX[2 * py + 1])[px];
                unsigned y0 = ((unsigned*)sY[2 * py])[px];
                unsigned y1 = ((unsigned*)sY[2 * py + 1])[px];
                vx = 0.25f * (bf2f(x0 & 0xffffu) + bf2f(x0 >> 16) +
                              bf2f(x1 & 0xffffu) + bf2f(x1 >> 16));
                vy = 0.25f * (bf2f(y0 & 0xffffu) + bf2f(y0 >> 16) +
                              bf2f(y1 & 0xffffu) + bf2f(y1 >> 16));
            } else {
                vx = 0.25f * (sX[2 * py][2 * px]     + sX[2 * py][2 * px + 1] +
                              sX[2 * py + 1][2 * px] + sX[2 * py + 1][2 * px + 1]);
                vy = 0.25f * (sY[2 * py][2 * px]     + sY[2 * py][2 * px + 1] +
                              sY[2 * py + 1][2 * px] + sY[2 * py + 1][2 * px + 1]);
            }
            size_t o = ((size_t)nc * pH + ppy) * pW + ppx;
            poolX[o] = vx;
            poolY[o] = vy;
        }
    }

    // ---- vertical blur: IWT cols x (VG full groups + optional tail) ----
    if (tid < VGT * IWT) {
        int rg = tid / IWT, c = tid - rg * IWT;
        if (rg < VG) {
            vblur_col<6, ET, LS, TBH>(sX, sY, vb, rg * 6, c, gw);
        } else if constexpr (VT > 0) {
            vblur_col<(VT > 0 ? VT : 1), ET, LS, TBH>(sX, sY, vb, VG * 6, c, gw);
        }
    }
    __syncthreads();

    // ---- horizontal blur + SSIM; 4 outputs/thread ----
    const float C1 = 1e-4f, C2 = 9e-4f;
    float locS2 = 0.f, locD = 0.f;
    {
        const int r  = tid / CG;                 // 0..TBH-1
        const int cb = (tid % CG) * 4;           // 0..TBW-4
        float st[5][4];
#pragma unroll
        for (int s = 0; s < 5; ++s) {
            float w[16];
            if constexpr (LP) {
                const uint2* p = (const uint2*)(&vb[s][r][cb]);  // 8B aligned
                uint2 q0 = p[0], q1 = p[1], q2 = p[2], q3 = p[3];
                unsigned wd[7] = {q0.x, q0.y, q1.x, q1.y, q2.x, q2.y, q3.x};
#pragma unroll
                for (int i = 0; i < 7; ++i) {
                    w[2 * i]     = bf2f(wd[i] & 0xffffu);
                    w[2 * i + 1] = bf2f(wd[i] >> 16);
                }
            } else {
                const float4* p = (const float4*)(&vb[s][r][cb]); // 16B aligned
                float4 q0 = p[0], q1 = p[1], q2 = p[2], q3 = p[3];
                float tmp[16] = {q0.x, q0.y, q0.z, q0.w, q1.x, q1.y, q1.z, q1.w,
                                 q2.x, q2.y, q2.z, q2.w, q3.x, q3.y, q3.z, q3.w};
#pragma unroll
                for (int i = 0; i < 16; ++i) w[i] = tmp[i];
            }
#pragma unroll
            for (int j = 0; j < 4; ++j) {
                float acc = 0.f;
#pragma unroll
                for (int k = 0; k < WIN; ++k) acc += gw.g[k] * w[j + k];
                st[s][j] = acc;
            }
        }
        const int oy = oy0 + r;
#pragma unroll
        for (int j = 0; j < 4; ++j) {
            int ox = ox0 + cb + j;
            if (oy < outH && ox < outW) {
                float mu1 = st[0][j], mu2 = st[1][j];
                float mu1sq = mu1 * mu1, mu2sq = mu2 * mu2, mu12 = mu1 * mu2;
                float s1  = st[2][j] - mu1sq;
                float s2v = st[3][j] - mu2sq;
                float s12 = st[4][j] - mu12;
                float S1 = (2.f * mu12 + C1) * __builtin_amdgcn_rcpf(mu1sq + mu2sq + C1);
                float S2 = (2.f * s12 + C2) * __builtin_amdgcn_rcpf(s1 + s2v + C2);
                float S  = S1 + S2;
                if (S > 2.f) S = 2.f;
                locS2 += S2;
                locD  += __builtin_amdgcn_sqrtf(2.f - S);
            }
        }
    }

    // ---- block reduction: wave shuffle, then NW wave partials ----
#pragma unroll
    for (int off = 32; off > 0; off >>= 1) {
        locS2 += __shfl_down(locS2, off);
        locD  += __shfl_down(locD,  off);
    }
    if ((tid & 63) == 0) {
        wpart[0][tid >> 6] = locS2;
        wpart[1][tid >> 6] = locD;
    }
    __syncthreads();
    if (tid == 0) {
        float s = 0.f, d = 0.f;
#pragma unroll
        for (int i = 0; i < NW; ++i) { s += wpart[0][i]; d += wpart[1][i]; }
        atomicAdd(&accS2[nc], s);
        atomicAdd(&accD[nc],  d);
    }
}

// ---------------------------------------------------------------------------
__global__ void zero_acc_kernel(float* acc, int n)
{
    int i = blockIdx.x * blockDim.x + threadIdx.x;
    if (i < n) acc[i] = 0.f;
}

// finalize: per-(n,c) weighted product over levels, mean -> scalar
// acc layout per level: [lvl*96 + 0..47] = sum S2, [lvl*96 + 48..95] = sum D
__global__ void finalize_kernel(const float* __restrict__ acc, float* __restrict__ out)
{
    int t = threadIdx.x;
    float v = 0.f;
    if (t < NCH) {
        const float w[5]   = {0.0448f, 0.2856f, 0.3001f, 0.2363f, 0.1333f};
        const float cnt[5] = {502.f * 502.f, 246.f * 246.f, 118.f * 118.f,
                              54.f * 54.f, 22.f * 22.f};
        float val = 1.f;
#pragma unroll
        for (int l = 0; l < 4; ++l) {
            float cs = fmaxf(acc[l * 96 + t] / cnt[l], 0.f);
            val *= powf(cs, w[l]);
        }
        float d = fmaxf(acc[4 * 96 + 48 + t] / cnt[4], 0.f);
        val *= powf(d, w[4]);
        v = val;
    }
#pragma unroll
    for (int off = 32; off > 0; off >>= 1) v += __shfl_down(v, off);
    if (t == 0) out[0] = v / (float)NCH;
}

// ---------------------------------------------------------------------------
static GaussW make_gauss()
{
    GaussW gw;
    double v[WIN], s = 0.0;
    for (int i = 0; i < WIN; ++i) {
        double c = (double)i - (WIN / 2);
        v[i] = exp(-c * c / (2.0 * 1.5 * 1.5));
        s += v[i];
    }
    for (int i = 0; i < WIN; ++i) gw.g[i] = (float)(v[i] / s);
    return gw;
}

extern "C" void kernel_launch(void* const* d_in, const int* in_sizes, int n_in,
                              void* d_out, int out_size, void* d_ws, size_t ws_size,
                              hipStream_t stream)
{
    const float* X0 = (const float*)d_in[0];
    const float* Y0 = (const float*)d_in[1];
    float* out = (float*)d_out;
    char*  ws  = (char*)d_ws;

    float* acc = (float*)ws;                 // 5 levels x 96 floats
    const int accN = 5 * 96;
    zero_acc_kernel<<<(accN + 255) / 256, 256, 0, stream>>>(acc, accN);

    float* pyr = (float*)(ws + 4096);
    GaussW gw = make_gauss();

    const float* curX = X0;
    const float* curY = Y0;
    float* nextbuf = pyr;
    int H = 512;

    for (int lvl = 0; lvl < 5; ++lvl) {
        int outH = H - HALO;

        float* nX = nullptr;
        float* nY = nullptr;
        if (lvl < 4) {
            int oh = H / 2;
            size_t elems = (size_t)NCH * oh * oh;
            nX = nextbuf;
            nY = nX + elems;
            nextbuf = nY + elems;
        }

        if (lvl < 2) {
            dim3 grid(H / 64, H / 32, NCH);
            ssim_level_kernel<true, 64, 32, 512><<<grid, 512, 0, stream>>>(
                curX, curY, H, H, outH, outH,
                acc + lvl * 96, acc + lvl * 96 + 48, nX, nY, gw);
        } else {
            int g = H / 32; if (g == 0) g = 1;
            dim3 grid(g, g, NCH);
            ssim_level_kernel<false, 32, 32, 256><<<grid, 256, 0, stream>>>(
                curX, curY, H, H, outH, outH,
                acc + lvl * 96, acc + lvl * 96 + 48, nX, nY, gw);
        }

        if (lvl < 4) {
            curX = nX;
            curY = nY;
            H >>= 1;
        }
    }

    finalize_kernel<<<1, 64, 0, stream>>>(acc, out);
}

// Round 8
// 206.559 us; speedup vs baseline: 1.2739x; 1.2739x over previous
//
#include <hip/hip_runtime.h>
#include <math.h>
#include <type_traits>

#define NCH 48            // N*C = 16*3
#define WIN 11
#define HALO 10

struct GaussW { float g[WIN]; };

// ---- bf16 <-> f32 bit helpers (RNE pack) ----
__device__ __forceinline__ float bf2f(unsigned u16) { return __uint_as_float(u16 << 16); }
__device__ __forceinline__ unsigned f2bf(float f)
{
    unsigned u = __float_as_uint(f);
    u += 0x7FFFu + ((u >> 16) & 1u);
    return u >> 16;
}
__device__ __forceinline__ float eload(const unsigned short* p) { return bf2f(*p); }
__device__ __forceinline__ float eload(const float* p)          { return *p; }
__device__ __forceinline__ void  estore(unsigned short* p, float v) { *p = (unsigned short)f2bf(v); }
__device__ __forceinline__ void  estore(float* p, float v)          { *p = v; }

// ---------------------------------------------------------------------------
// 4-signal trick: blur {x, y, q=x^2+y^2, dd=(x-y)^2}.
//   sigma1^2+sigma2^2 = blur(q) - mu1^2 - mu2^2
//   2*sigma12         = blur(q) - blur(dd) - 2*mu1*mu2
// 20% fewer blur FMAs / vb LDS than the 5-signal form.
// ---------------------------------------------------------------------------

// vertical blur of NOUT consecutive output rows at one column.
// sXc=&sX[r0][c]; vbc=&vb[0][r0_local][c]; PS = plane stride (elements).
template<int NOUT, typename ET, int LS, int PS>
__device__ __forceinline__ void vblur_col(const ET* sXc, const ET* sYc, ET* vbc,
                                          const GaussW& gw)
{
    float a0[NOUT], a1[NOUT], a2[NOUT], a3[NOUT];
#pragma unroll
    for (int j = 0; j < NOUT; ++j) { a0[j] = a1[j] = a2[j] = a3[j] = 0.f; }
#pragma unroll
    for (int i = 0; i < NOUT + 10; ++i) {
        float xv = eload(sXc + i * LS);
        float yv = eload(sYc + i * LS);
        float q  = xv * xv + yv * yv;
        float t  = xv - yv;
        float dd = t * t;
#pragma unroll
        for (int j = 0; j < NOUT; ++j) {
            int k = i - j;
            if (k >= 0 && k < WIN) {
                float gv = gw.g[k];
                a0[j] += gv * xv;
                a1[j] += gv * yv;
                a2[j] += gv * q;
                a3[j] += gv * dd;
            }
        }
    }
#pragma unroll
    for (int j = 0; j < NOUT; ++j) {
        estore(vbc + 0 * PS + j * LS, a0[j]);
        estore(vbc + 1 * PS + j * LS, a1[j]);
        estore(vbc + 2 * PS + j * LS, a2[j]);
        estore(vbc + 3 * PS + j * LS, a3[j]);
    }
}

// horizontal blur of the 4 vb planes + SSIM for 4 outputs (cols cb..cb+3, row r)
template<typename ET, int LS, int PS, bool NEED_D>
__device__ __forceinline__ void hssim(const ET* vbb, int r, int cb,
                                      int oy, int ox0c, int outH, int outW,
                                      const GaussW& gw, float& locS2, float& locD)
{
    const float C1 = 1e-4f, C2 = 9e-4f;
    float st[4][4];
#pragma unroll
    for (int s = 0; s < 4; ++s) {
        float w[16];
        const ET* base = vbb + s * PS + r * LS + cb;
        if constexpr (std::is_same<ET, unsigned short>::value) {
            const uint2* p = (const uint2*)base;                 // 8B aligned
            uint2 q0 = p[0], q1 = p[1], q2 = p[2], q3 = p[3];
            unsigned wd[7] = {q0.x, q0.y, q1.x, q1.y, q2.x, q2.y, q3.x};
#pragma unroll
            for (int i = 0; i < 7; ++i) {
                w[2 * i]     = bf2f(wd[i] & 0xffffu);
                w[2 * i + 1] = bf2f(wd[i] >> 16);
            }
            w[14] = w[15] = 0.f;
        } else {
            const float4* p = (const float4*)base;               // 16B aligned
            float4 q0 = p[0], q1 = p[1], q2 = p[2], q3 = p[3];
            float tmp[16] = {q0.x, q0.y, q0.z, q0.w, q1.x, q1.y, q1.z, q1.w,
                             q2.x, q2.y, q2.z, q2.w, q3.x, q3.y, q3.z, q3.w};
#pragma unroll
            for (int i = 0; i < 16; ++i) w[i] = tmp[i];
        }
#pragma unroll
        for (int j = 0; j < 4; ++j) {
            float acc = 0.f;
#pragma unroll
            for (int k = 0; k < WIN; ++k) acc += gw.g[k] * w[j + k];
            st[s][j] = acc;
        }
    }
#pragma unroll
    for (int j = 0; j < 4; ++j) {
        int ox = ox0c + j;
        if (oy < outH && ox < outW) {
            float mu1 = st[0][j], mu2 = st[1][j], bq = st[2][j], bdd = st[3][j];
            float m11 = mu1 * mu1, m22 = mu2 * mu2, m12 = mu1 * mu2;
            float den2 = bq - m11 - m22 + C2;
            float num2 = bq - bdd - 2.f * m12 + C2;
            float S2 = num2 * __builtin_amdgcn_rcpf(den2);
            locS2 += S2;
            if constexpr (NEED_D) {
                float S1 = (2.f * m12 + C1) * __builtin_amdgcn_rcpf(m11 + m22 + C1);
                float S = S1 + S2;
                if (S > 2.f) S = 2.f;
                locD += __builtin_amdgcn_sqrtf(2.f - S);
            }
        }
    }
}

// ---------------------------------------------------------------------------
// Generic per-level kernel (levels 0-2): one block = TBWxTBH tile of one nc.
// Writes its block-partial S2 sum to pS2[bId] (no atomics -> no zero pass).
// LP=true: bf16 LDS (L0/L1; sigma denominators large there). LP=false: fp32.
// launch_bounds(.,4): VGPR cap 128 -> no spills (R5/R6 lesson).
// ---------------------------------------------------------------------------
template<bool LP, int TBW, int TBH, int NTH>
__global__ __launch_bounds__(NTH, 4)
void ssim_level_kernel(const float* __restrict__ X, const float* __restrict__ Y,
                       int H, int W, int outH, int outW,
                       float* __restrict__ pS2,
                       float* __restrict__ poolX, float* __restrict__ poolY,
                       GaussW gw)
{
    using ET = std::conditional_t<LP, unsigned short, float>;
    constexpr int IWT   = TBW + HALO;
    constexpr int IHT   = TBH + HALO;
    constexpr int LS    = LP ? ((IWT + 7) & ~7) : ((IWT + 3) & ~3);
    constexpr int PS    = TBH * LS;
    constexpr int NW    = NTH / 64;
    constexpr int PAIRS = IWT / 2;
    constexpr int VG    = TBH / 6;
    constexpr int VT    = TBH % 6;
    constexpr int VGT   = VG + (VT ? 1 : 0);
    constexpr int CG    = TBW / 4;

    const int nc  = blockIdx.z;
    const int oy0 = blockIdx.y * TBH;
    const int ox0 = blockIdx.x * TBW;
    const int tid = threadIdx.x;

    const float* __restrict__ Xp = X + (size_t)nc * H * W;
    const float* __restrict__ Yp = Y + (size_t)nc * H * W;

    __shared__ __align__(16) ET sX[IHT][LS];
    __shared__ __align__(16) ET sY[IHT][LS];
    __shared__ __align__(16) ET vb[4][TBH][LS];
    __shared__ float wpart[NW];

    // ---- stage input tile; OOB -> 0 ----
    for (int l = tid; l < IHT * PAIRS; l += NTH) {
        int r  = l / PAIRS, cp = l - r * PAIRS;
        int gy = oy0 + r, gx = ox0 + 2 * cp;
        float2 xv = make_float2(0.f, 0.f), yv = xv;
        if (gy < H && gx < W) {
            size_t idx = (size_t)gy * W + gx;
            xv = *(const float2*)(Xp + idx);
            yv = *(const float2*)(Yp + idx);
        }
        if constexpr (LP) {
            ((unsigned*)sX[r])[cp] = f2bf(xv.x) | (f2bf(xv.y) << 16);
            ((unsigned*)sY[r])[cp] = f2bf(yv.x) | (f2bf(yv.y) << 16);
        } else {
            sX[r][2 * cp]     = xv.x;
            sX[r][2 * cp + 1] = xv.y;
            sY[r][2 * cp]     = yv.x;
            sY[r][2 * cp + 1] = yv.y;
        }
    }
    __syncthreads();

    // ---- fused 2x2 avg-pool of raw TBWxTBH quadrant ----
    {
        int py = tid / (TBW / 2), px = tid % (TBW / 2);
        int pH = H >> 1, pW = W >> 1;
        int ppy = (oy0 >> 1) + py, ppx = (ox0 >> 1) + px;
        if (ppy < pH && ppx < pW) {
            float vx, vy;
            if constexpr (LP) {
                unsigned x0 = ((unsigned*)sX[2 * py])[px];
                unsigned x1 = ((unsigned*)sX[2 * py + 1])[px];
                unsigned y0 = ((unsigned*)sY[2 * py])[px];
                unsigned y1 = ((unsigned*)sY[2 * py + 1])[px];
                vx = 0.25f * (bf2f(x0 & 0xffffu) + bf2f(x0 >> 16) +
                              bf2f(x1 & 0xffffu) + bf2f(x1 >> 16));
                vy = 0.25f * (bf2f(y0 & 0xffffu) + bf2f(y0 >> 16) +
                              bf2f(y1 & 0xffffu) + bf2f(y1 >> 16));
            } else {
                vx = 0.25f * (sX[2 * py][2 * px]     + sX[2 * py][2 * px + 1] +
                              sX[2 * py + 1][2 * px] + sX[2 * py + 1][2 * px + 1]);
                vy = 0.25f * (sY[2 * py][2 * px]     + sY[2 * py][2 * px + 1] +
                              sY[2 * py + 1][2 * px] + sY[2 * py + 1][2 * px + 1]);
            }
            size_t o = ((size_t)nc * pH + ppy) * pW + ppx;
            poolX[o] = vx;
            poolY[o] = vy;
        }
    }

    // ---- vertical blur ----
    if (tid < VGT * IWT) {
        int rg = tid / IWT, c = tid - rg * IWT;
        if (rg < VG) {
            vblur_col<6, ET, LS, PS>(&sX[rg * 6][c], &sY[rg * 6][c],
                                     &vb[0][rg * 6][c], gw);
        } else if constexpr (VT > 0) {
            vblur_col<(VT > 0 ? VT : 1), ET, LS, PS>(&sX[VG * 6][c], &sY[VG * 6][c],
                                                     &vb[0][VG * 6][c], gw);
        }
    }
    __syncthreads();

    // ---- horizontal blur + SSIM (S2 only at levels 0-2) ----
    float locS2 = 0.f, locD = 0.f;
    {
        const int r  = tid / CG;
        const int cb = (tid % CG) * 4;
        hssim<ET, LS, PS, false>(&vb[0][0][0], r, cb, oy0 + r, ox0 + cb,
                                 outH, outW, gw, locS2, locD);
    }

    // ---- block reduce -> one partial slot per block ----
#pragma unroll
    for (int off = 32; off > 0; off >>= 1) locS2 += __shfl_down(locS2, off);
    if ((tid & 63) == 0) wpart[tid >> 6] = locS2;
    __syncthreads();
    if (tid == 0) {
        float s = 0.f;
#pragma unroll
        for (int i = 0; i < NW; ++i) s += wpart[i];
        int bId = (blockIdx.z * gridDim.y + blockIdx.y) * gridDim.x + blockIdx.x;
        pS2[bId] = s;
    }
}

// ---------------------------------------------------------------------------
// block-wide sum (valid on tid 0). Internal syncs make repeated calls safe.
__device__ __forceinline__ float block_sum8(float v, float* wp, int tid)
{
#pragma unroll
    for (int off = 32; off > 0; off >>= 1) v += __shfl_down(v, off);
    __syncthreads();
    if ((tid & 63) == 0) wp[tid >> 6] = v;
    __syncthreads();
    float s = 0.f;
    if (tid == 0) {
#pragma unroll
        for (int i = 0; i < 8; ++i) s += wp[i];
    }
    return s;
}

// ---------------------------------------------------------------------------
// Tail kernel: one block per nc (48 blocks, 512 threads). Does level 3
// (64x64, fp32, two 30/24-row bands to bound LDS), pools to level 4 in LDS,
// does level 4 (with D), then folds in the level 0-2 block partials and
// writes the per-nc weighted product.
// ---------------------------------------------------------------------------
__global__ __launch_bounds__(512, 1)
void ssim_tail_kernel(const float* __restrict__ X3, const float* __restrict__ Y3,
                      const float* __restrict__ p0, const float* __restrict__ p1,
                      const float* __restrict__ p2,
                      float* __restrict__ vals, GaussW gw)
{
    constexpr int IW3 = 74, LS3 = 76, O3 = 54;
    constexpr int LS4 = 44, O4 = 22;

    const int nc  = blockIdx.x;
    const int tid = threadIdx.x;
    const float* __restrict__ Xp = X3 + (size_t)nc * 64 * 64;
    const float* __restrict__ Yp = Y3 + (size_t)nc * 64 * 64;

    __shared__ __align__(16) float sX[64][LS3];
    __shared__ __align__(16) float sY[64][LS3];
    __shared__ __align__(16) float vbraw[4 * 30 * LS3];   // band vb3 / L4 scratch
    __shared__ __align__(16) float pX[32][34];
    __shared__ __align__(16) float pY[32][34];
    __shared__ float wpart[8];

    // ---- stage full L3 image (cols 64..73 zero) ----
    for (int l = tid; l < 64 * IW3; l += 512) {
        int r = l / IW3, c = l - r * IW3;
        float xv = 0.f, yv = 0.f;
        if (c < 64) { xv = Xp[r * 64 + c]; yv = Yp[r * 64 + c]; }
        sX[r][c] = xv;
        sY[r][c] = yv;
    }
    __syncthreads();

    // ---- pool L3 -> L4 (32x32) into LDS ----
    for (int l = tid; l < 1024; l += 512) {
        int py = l >> 5, px = l & 31;
        pX[py][px] = 0.25f * (sX[2 * py][2 * px]     + sX[2 * py][2 * px + 1] +
                              sX[2 * py + 1][2 * px] + sX[2 * py + 1][2 * px + 1]);
        pY[py][px] = 0.25f * (sY[2 * py][2 * px]     + sY[2 * py][2 * px + 1] +
                              sY[2 * py + 1][2 * px] + sY[2 * py + 1][2 * px + 1]);
    }

    // ---- L3 SSIM in two row-bands (rows 0..29, 30..53) ----
    float locS2 = 0.f, locD = 0.f, scrap = 0.f;
    for (int b = 0; b < 2; ++b) {
        const int r0b = 30 * b;
        const int ng  = b ? 4 : 5;          // 6-row vblur groups
        const int nr  = b ? 24 : 30;        // output rows in band
        for (int g = tid; g < ng * IW3; g += 512) {
            int rg = g / IW3, c = g - rg * IW3;
            int r0 = r0b + rg * 6;
            vblur_col<6, float, LS3, 30 * LS3>(&sX[r0][c], &sY[r0][c],
                                               &vbraw[rg * 6 * LS3 + c], gw);
        }
        __syncthreads();
        for (int t = tid; t < nr * 14; t += 512) {
            int rl = t / 14, cg = t - rl * 14;
            int cb = cg * 4;
            hssim<float, LS3, 30 * LS3, false>(vbraw, rl, cb, r0b + rl, cb,
                                               O3, O3, gw, locS2, locD);
        }
        __syncthreads();
    }

    // ---- L4 phase: reuse vbraw for staging + vb4 ----
    float (*sX4)[LS4] = (float(*)[LS4])vbraw;                 // 32 x 44
    float (*sY4)[LS4] = (float(*)[LS4])(vbraw + 32 * LS4);
    float* vb4        = vbraw + 2 * 32 * LS4;                 // 4 x 22 x 44
    for (int l = tid; l < 32 * 42; l += 512) {
        int r = l / 42, c = l - r * 42;
        sX4[r][c] = (c < 32) ? pX[r][c] : 0.f;
        sY4[r][c] = (c < 32) ? pY[r][c] : 0.f;
    }
    __syncthreads();
    if (tid < 4 * 42) {                                       // vblur: 22 rows
        int rg = tid / 42, c = tid - rg * 42;
        if (rg < 3)
            vblur_col<6, float, LS4, 22 * LS4>(&sX4[rg * 6][c], &sY4[rg * 6][c],
                                               vb4 + rg * 6 * LS4 + c, gw);
        else
            vblur_col<4, float, LS4, 22 * LS4>(&sX4[18][c], &sY4[18][c],
                                               vb4 + 18 * LS4 + c, gw);
    }
    __syncthreads();
    float s2_4 = 0.f;
    if (tid < 22 * 6) {                                       // hblur: 22x22 out
        int r = tid / 6, cb = (tid % 6) * 4;
        hssim<float, LS4, 22 * LS4, true>(vb4, r, cb, r, cb, O4, O4, gw, s2_4, locD);
    }

    // ---- reductions + per-nc weighted product ----
    float s3 = block_sum8(locS2, wpart, tid);
    float d4 = block_sum8(locD, wpart, tid);
    float c0 = block_sum8((tid < 128) ? p0[nc * 128 + tid] : 0.f, wpart, tid);
    float c1 = block_sum8((tid < 32)  ? p1[nc * 32 + tid]  : 0.f, wpart, tid);
    float c2 = block_sum8((tid < 16)  ? p2[nc * 16 + tid]  : 0.f, wpart, tid);
    if (tid == 0) {
        const float w0 = 0.0448f, w1 = 0.2856f, w2 = 0.3001f, w3 = 0.2363f, w4 = 0.1333f;
        float cs0 = fmaxf(c0 / (502.f * 502.f), 0.f);
        float cs1 = fmaxf(c1 / (246.f * 246.f), 0.f);
        float cs2 = fmaxf(c2 / (118.f * 118.f), 0.f);
        float cs3 = fmaxf(s3 / (54.f * 54.f), 0.f);
        float dd4 = fmaxf(d4 / (22.f * 22.f), 0.f);
        vals[nc] = powf(cs0, w0) * powf(cs1, w1) * powf(cs2, w2) *
                   powf(cs3, w3) * powf(dd4, w4);
    }
}

// ---------------------------------------------------------------------------
__global__ void finalize_kernel(const float* __restrict__ vals, float* __restrict__ out)
{
    int t = threadIdx.x;
    float v = (t < NCH) ? vals[t] : 0.f;
#pragma unroll
    for (int off = 32; off > 0; off >>= 1) v += __shfl_down(v, off);
    if (t == 0) out[0] = v / (float)NCH;
}

// ---------------------------------------------------------------------------
static GaussW make_gauss()
{
    GaussW gw;
    double v[WIN], s = 0.0;
    for (int i = 0; i < WIN; ++i) {
        double c = (double)i - (WIN / 2);
        v[i] = exp(-c * c / (2.0 * 1.5 * 1.5));
        s += v[i];
    }
    for (int i = 0; i < WIN; ++i) gw.g[i] = (float)(v[i] / s);
    return gw;
}

extern "C" void kernel_launch(void* const* d_in, const int* in_sizes, int n_in,
                              void* d_out, int out_size, void* d_ws, size_t ws_size,
                              hipStream_t stream)
{
    const float* X0 = (const float*)d_in[0];
    const float* Y0 = (const float*)d_in[1];
    float* out = (float*)d_out;
    float* ws  = (float*)d_ws;

    // partial-sum slots (written unconditionally -> no zeroing needed)
    float* p0   = ws;                      // 48*128
    float* p1   = p0 + NCH * 128;          // 48*32
    float* p2   = p1 + NCH * 32;           // 48*16
    float* vals = p2 + NCH * 16;           // 48
    float* pyr  = ws + 16384;              // 64 KB in, 16-byte aligned

    float* pyr1X = pyr;                    // 48*256*256
    float* pyr1Y = pyr1X + (size_t)NCH * 256 * 256;
    float* pyr2X = pyr1Y + (size_t)NCH * 256 * 256;
    float* pyr2Y = pyr2X + (size_t)NCH * 128 * 128;
    float* pyr3X = pyr2Y + (size_t)NCH * 128 * 128;
    float* pyr3Y = pyr3X + (size_t)NCH * 64 * 64;

    GaussW gw = make_gauss();

    // L0: 512 -> partials p0, pool -> pyr1
    ssim_level_kernel<true, 64, 32, 512><<<dim3(8, 16, NCH), 512, 0, stream>>>(
        X0, Y0, 512, 512, 502, 502, p0, pyr1X, pyr1Y, gw);
    // L1: 256 -> p1, pool -> pyr2
    ssim_level_kernel<true, 64, 32, 512><<<dim3(4, 8, NCH), 512, 0, stream>>>(
        pyr1X, pyr1Y, 256, 256, 246, 246, p1, pyr2X, pyr2Y, gw);
    // L2: 128 (fp32) -> p2, pool -> pyr3
    ssim_level_kernel<false, 32, 32, 256><<<dim3(4, 4, NCH), 256, 0, stream>>>(
        pyr2X, pyr2Y, 128, 128, 118, 118, p2, pyr3X, pyr3Y, gw);
    // L3+L4+per-nc product
    ssim_tail_kernel<<<NCH, 512, 0, stream>>>(pyr3X, pyr3Y, p0, p1, p2, vals, gw);
    // mean over nc
    finalize_kernel<<<1, 64, 0, stream>>>(vals, out);
}